// Round 8
// baseline (76.825 us; speedup 1.0000x reference)
//
#include <hip/hip_runtime.h>
#include <math.h>

#define HIN 32
#define WIN 32
#define NITER 3

// R3: ilds row stride 96 with per-8-channel pad (c + 4*(c>>3)) so the 8
// s-groups start at s*12 floats: distinct mod-32 banks.
#define IROW 96

typedef float f2 __attribute__((ext_vector_type(2)));
static __device__ __forceinline__ f2 mk2(float a, float b) { f2 r; r.x = a; r.y = b; return r; }
static __device__ __forceinline__ f2 fma2(f2 a, f2 b, f2 c) { return __builtin_elementwise_fma(a, b, c); }

// ---- 8-lane sum entirely on the VALU pipe (DPP), no ds_swizzle ----
template <int CTRL>
__device__ __forceinline__ float dpp_add(float v) {
    int p = __builtin_amdgcn_update_dpp(0, __float_as_int(v), CTRL, 0xF, 0xF, true);
    return v + __int_as_float(p);
}
__device__ __forceinline__ float sum8(float v) {
    v = dpp_add<0xB1>(v);   // quad_perm xor1
    v = dpp_add<0x4E>(v);   // quad_perm xor2
    v = dpp_add<0x141>(v);  // row_half_mirror
    return v;
}

// ---- stage T taps of flipped weight into pk layout ----
//   wlds[vtap*640 + g*80 + rot(g,m2)*20 + l*2 + h]
// R3 rot = (m2 + (g>>1)) & 3: bank-quad (4g+5*rot) mod 8 is a permutation.
template <int TH, int TW>
__device__ __forceinline__ void stage_weights(const float* __restrict__ weight,
                                              float* __restrict__ wlds, int t) {
    constexpr int T = TH * TW;
    const int sg = (t >> 3) & 7;
    const int sm = t & 7;
    const int l0 = t >> 6;
    const int dbase = sg * 80 + (((sm >> 1) + (sg >> 1)) & 3) * 20 + (sm & 1);
#pragma unroll
    for (int k = 0; k < 2 * T; ++k) {
        const int vtap = k >> 1;
        const int chunk = k & 1;
        const int hh = (TH == 1) ? 1 : ((vtap / TW) * 2);
        const int ww = (TW == 1) ? 1 : ((vtap % TW) * 2);
        const int jflip = (2 - hh) * 3 + (2 - ww);  // compile-time flip
        const int l = chunk * 4 + l0;
        wlds[vtap * 640 + dbase + l * 2] = weight[(chunk * 256 + t) * 9 + jflip];
    }
}

// ---- stage the block's input tile [yi][xi<12][cpad] (zero-filled OOB) ----
template <int NROWS, int NCHUNK>
__device__ __forceinline__ void stage_input(const float* __restrict__ in,
                                            float* __restrict__ ilds,
                                            int t, int n, int y0, int x0) {
    const int c = t >> 2, r = t & 3;
    const int cpad = c + 4 * (c >> 3);  // R3: bank-spread channel offset
#pragma unroll
    for (int pp = r; pp < NROWS * NCHUNK; pp += 4) {
        const int yi = pp / NCHUNK, ch = pp % NCHUNK; // compile-time folds
        const int y = y0 + yi;
        const int xc = x0 + ch * 4;
        float4 vv = {0.f, 0.f, 0.f, 0.f};
        if (y < HIN && xc < WIN)
            vv = *(const float4*)(in + (((size_t)(n * 64 + c) * HIN + y) * WIN + xc));
        ilds[(yi * 12 + ch * 4 + 0) * IROW + cpad] = vv.x;
        ilds[(yi * 12 + ch * 4 + 1) * IROW + cpad] = vv.y;
        ilds[(yi * 12 + ch * 4 + 2) * IROW + cpad] = vv.z;
        ilds[(yi * 12 + ch * 4 + 3) * IROW + cpad] = vv.w;
    }
}

// ---- priors for one position q (m-dim packed f2; invalid taps -> zero votes)
template <int TH, int TW>
__device__ __forceinline__ void compute_pri(const float* __restrict__ ilds,
                                            const float* __restrict__ wlds,
                                            int q, int x0, int pi, int g, int s,
                                            f2 (&pri2)[TH * TW][4]) {
#pragma unroll
    for (int i = 0; i < TH; ++i) {
        const int y = (TH == 1) ? pi : (pi + i);
        const bool vy = (y < HIN);
#pragma unroll
        for (int j = 0; j < TW; ++j) {
            const int v = i * TW + j;
            const int w = (TW == 1) ? 1 : j * 2;
            const int x = (q + w - 1) >> 1;
            if (vy && x < WIN) {  // wave-uniform
                const float4* xp =
                    (const float4*)(ilds + (i * 12 + (x - x0)) * IROW + s * 12);
                float4 x0v = xp[0], x1v = xp[1];
                float xv[8] = {x0v.x, x0v.y, x0v.z, x0v.w, x1v.x, x1v.y, x1v.z, x1v.w};
                const float* wb = wlds + v * 640 + g * 80;
#pragma unroll
                for (int m2 = 0; m2 < 4; ++m2) {
                    const float4* row =
                        (const float4*)(wb + ((m2 + (g >> 1)) & 3) * 20);  // R3 rot
                    f2 acc = mk2(0.f, 0.f);
#pragma unroll
                    for (int k = 0; k < 4; ++k) {
                        float4 w4 = row[k];
                        acc = fma2(mk2(xv[2 * k], xv[2 * k]), mk2(w4.x, w4.y), acc);
                        acc = fma2(mk2(xv[2 * k + 1], xv[2 * k + 1]), mk2(w4.z, w4.w), acc);
                    }
                    pri2[v][m2] = acc;
                }
            } else {
#pragma unroll
                for (int m2 = 0; m2 < 4; ++m2) pri2[v][m2] = mk2(0.f, 0.f);
            }
        }
    }
}

// ---- full routing for one position: unnormalized r[] carried across iters
// (normalize is scale-invariant); zero votes add Z = 72-8T to the deferred
// softmax denominator. exp2-domain softmax (R0), exact rewrite.
template <int T>
__device__ __forceinline__ float route_core(const f2 (&pri2)[T][4],
                                            const float* __restrict__ bias,
                                            int g, int s) {
    constexpr float Z = (float)(72 - 8 * T);
    f2 rr[4];
#pragma unroll
    for (int m2 = 0; m2 < 4; ++m2) {
        f2 a = mk2(0.f, 0.f);
#pragma unroll
        for (int v = 0; v < T; ++v) a += pri2[v][m2];
        rr[m2].x = sum8(a.x);
        rr[m2].y = sum8(a.y);
    }
    float r8v = 0.f;
#pragma unroll
    for (int it = 0; it < NITER; ++it) {
        f2 t2 = mk2(0.f, 0.f);
#pragma unroll
        for (int m2 = 0; m2 < 4; ++m2) t2 = fma2(rr[m2], rr[m2], t2);
        const float sn = t2.x + t2.y;
        const float inv = __builtin_amdgcn_rsqf(fmaxf(sn, 1e-24f)) * 1.44269504f;
        const f2 inv2 = mk2(inv, inv);
        f2 on2[4];
#pragma unroll
        for (int m2 = 0; m2 < 4; ++m2) on2[m2] = rr[m2] * inv2;

        float a8 = 0.f;
        f2 acc2[4];
#pragma unroll
        for (int m2 = 0; m2 < 4; ++m2) acc2[m2] = mk2(0.f, 0.f);
#pragma unroll
        for (int v = 0; v < T; ++v) {
            f2 d2 = mk2(0.f, 0.f);
#pragma unroll
            for (int m2 = 0; m2 < 4; ++m2) d2 = fma2(pri2[v][m2], on2[m2], d2);
            const float e = __builtin_exp2f(d2.x + d2.y);
            a8 += e;
            const f2 e2 = mk2(e, e);
#pragma unroll
            for (int m2 = 0; m2 < 4; ++m2) acc2[m2] = fma2(e2, pri2[v][m2], acc2[m2]);
        }
#pragma unroll
        for (int m2 = 0; m2 < 4; ++m2) {
            rr[m2].x = sum8(acc2[m2].x);
            rr[m2].y = sum8(acc2[m2].y);
        }
        if (it == NITER - 1) r8v = sum8(a8);
    }
    const float invs = __builtin_amdgcn_rcpf(r8v + Z);  // zero votes: exp2(0)=1
    const f2 invs2 = mk2(invs, invs);
    f2 o2[4];
#pragma unroll
    for (int m2 = 0; m2 < 4; ++m2) o2[m2] = rr[m2] * invs2;
    f2 s2 = mk2(0.f, 0.f);
#pragma unroll
    for (int m2 = 0; m2 < 4; ++m2) s2 = fma2(o2[m2], o2[m2], s2);
    const float sn = s2.x + s2.y;
    const float factor =
        sn * __builtin_amdgcn_rcpf(1.f + sn) * __builtin_amdgcn_rsqf(sn + 1e-12f);
    f2 osel = o2[0];
#pragma unroll
    for (int m2 = 1; m2 < 4; ++m2)
        if ((s >> 1) == m2) osel = o2[m2];
    float val = (s & 1) ? osel.y : osel.x;
    return val * factor + bias[g * 8 + s];
}

// ---- dual-position path (T<=2): one wave does q and q+8, sharing every
// weight ds_read between the two positions. Block covers 8 positions.
template <int TH, int TW>
__device__ __forceinline__ void run_dual(
    const float* __restrict__ in, const float* __restrict__ weight,
    const float* __restrict__ bias, float* __restrict__ out,
    float* __restrict__ ilds, float* __restrict__ wlds, float* __restrict__ olds,
    int t, int n, int p, int pi, int qb, int x0) {
    constexpr int T = TH * TW;
    stage_input<TH, (TW == 2 ? 3 : 2)>(in, ilds, t, n, pi, x0);
    stage_weights<TH, TW>(weight, wlds, t);
    __syncthreads();

    const int wave = t >> 6;
    const int lane = t & 63;
    const int g = lane >> 3;
    const int s = lane & 7;
    const int qa = qb + 2 * wave;

    f2 pa[T][4], pb[T][4];
    compute_pri<TH, TW>(ilds, wlds, qa, x0, pi, g, s, pa);
    compute_pri<TH, TW>(ilds, wlds, qa + 8, x0, pi, g, s, pb);

    const float va = route_core<T>(pa, bias, g, s);
    const float vb = route_core<T>(pb, bias, g, s);

    olds[lane * 9 + wave] = va;
    olds[lane * 9 + wave + 4] = vb;
    __syncthreads();
    const int c2 = t >> 2, w = t & 3;
    float* ob = out + (((size_t)n * 64 + c2) * 64 + p) * 64 + qb;
    ob[2 * w] = olds[c2 * 9 + w];
    ob[2 * w + 8] = olds[c2 * 9 + w + 4];
}

// ---- T=4 path: single position/wave ----
__device__ __forceinline__ void run_t4(
    const float* __restrict__ in, const float* __restrict__ weight,
    const float* __restrict__ bias, float* __restrict__ out,
    float* __restrict__ ilds, float* __restrict__ wlds, float* __restrict__ olds,
    int t, int n, int p, int pi, int qb, int x0) {
    stage_input<2, 2>(in, ilds, t, n, pi, x0);
    stage_weights<2, 2>(weight, wlds, t);
    __syncthreads();

    const int wave = t >> 6;
    const int lane = t & 63;
    const int g = lane >> 3;
    const int s = lane & 7;

    f2 pa[4][4];
    compute_pri<2, 2>(ilds, wlds, qb + 2 * wave, x0, pi, g, s, pa);
    const float va = route_core<4>(pa, bias, g, s);

    olds[lane * 5 + wave] = va;
    __syncthreads();
    const int c2 = t >> 2, w = t & 3;
    out[(((size_t)n * 64 + c2) * 64 + p) * 64 + qb + 2 * w] = olds[c2 * 5 + w];
}

// R6: EXACT revert to R3 structure (best measured: 66.48 at 1x launch).
// Grid 1280, quadrant-interleaved: blockIdx%5 -> {T4,T4,T2v,T2h,T1}.
__global__ __launch_bounds__(256, 5) void caps_routing(
    const float* __restrict__ in, const float* __restrict__ weight,
    const float* __restrict__ bias, float* __restrict__ out) {
    __shared__ float ilds[2 * 12 * IROW];  // input tile [yi][xi][cpad]
    __shared__ float wlds[4 * 640];        // staged taps (pk layout)
    __shared__ float olds[576];            // output staging
    const int t = threadIdx.x;

    const int b = blockIdx.x;
    const int grp = b / 5;        // 0..255
    const int sel = b - grp * 5;  // 0..4

    if (sel < 2) {  // T4: p odd, q odd; 512 blocks, 4 positions each
        const int idx = grp * 2 + sel;
        const int n = idx >> 8, r = idx & 255;
        const int pi = r >> 3, jq = r & 7;
        run_t4(in, weight, bias, out, ilds, wlds, olds,
               t, n, 2 * pi + 1, pi, 8 * jq + 1, 4 * jq);
    } else {  // dual paths: 256 blocks each, 8 positions each
        const int n = grp >> 7, r = grp & 127;
        const int pi = r >> 2, jq = r & 3;
        if (sel == 2)       // T2v: p odd, q even
            run_dual<2, 1>(in, weight, bias, out, ilds, wlds, olds,
                           t, n, 2 * pi + 1, pi, 16 * jq, 8 * jq);
        else if (sel == 3)  // T2h: p even, q odd
            run_dual<1, 2>(in, weight, bias, out, ilds, wlds, olds,
                           t, n, 2 * pi, pi, 16 * jq + 1, 8 * jq);
        else                // T1: p even, q even
            run_dual<1, 1>(in, weight, bias, out, ilds, wlds, olds,
                           t, n, 2 * pi, pi, 16 * jq, 8 * jq);
    }
}

extern "C" void kernel_launch(void* const* d_in, const int* in_sizes, int n_in,
                              void* d_out, int out_size, void* d_ws, size_t ws_size,
                              hipStream_t stream) {
    const float* in = (const float*)d_in[0];
    const float* weight = (const float*)d_in[1];
    const float* bias = (const float*)d_in[2];
    float* out = (float*)d_out;
    (void)d_ws; (void)ws_size;

    // R6/R7 instrumentation: the kernel is idempotent (deterministic, same
    // output both times), so launching it TWICE turns dur_us into a direct
    // kernel timer: k = dur_us(this round) - 66.48 (R3's 1x measurement).
    // The kernel never appears in rocprof top-5 (the 40us poison-fill
    // outranks it) — this is the only channel to measure it.
    caps_routing<<<1280, 256, 0, stream>>>(in, weight, bias, out);
    caps_routing<<<1280, 256, 0, stream>>>(in, weight, bias, out);
}

// Round 9
// 65.945 us; speedup vs baseline: 1.1650x; 1.1650x over previous
//
#include <hip/hip_runtime.h>
#include <math.h>

#define HIN 32
#define WIN 32
#define NITER 3

// R3: ilds row stride 96 with per-8-channel pad (c + 4*(c>>3)) so the 8
// s-groups start at s*12 floats: distinct mod-32 banks.
#define IROW 96

typedef float f2 __attribute__((ext_vector_type(2)));
static __device__ __forceinline__ f2 mk2(float a, float b) { f2 r; r.x = a; r.y = b; return r; }
static __device__ __forceinline__ f2 fma2(f2 a, f2 b, f2 c) { return __builtin_elementwise_fma(a, b, c); }

// ---- 8-lane sum entirely on the VALU pipe (DPP), no ds_swizzle ----
template <int CTRL>
__device__ __forceinline__ float dpp_add(float v) {
    int p = __builtin_amdgcn_update_dpp(0, __float_as_int(v), CTRL, 0xF, 0xF, true);
    return v + __int_as_float(p);
}
__device__ __forceinline__ float sum8(float v) {
    v = dpp_add<0xB1>(v);   // quad_perm xor1
    v = dpp_add<0x4E>(v);   // quad_perm xor2
    v = dpp_add<0x141>(v);  // row_half_mirror
    return v;
}

// ---- stage T taps of flipped weight into pk layout ----
//   wlds[vtap*640 + g*80 + rot(g,m2)*20 + l*2 + h]
// R3 rot = (m2 + (g>>1)) & 3: bank-quad (4g+5*rot) mod 8 is a permutation.
template <int TH, int TW>
__device__ __forceinline__ void stage_weights(const float* __restrict__ weight,
                                              float* __restrict__ wlds, int t) {
    constexpr int T = TH * TW;
    const int sg = (t >> 3) & 7;
    const int sm = t & 7;
    const int l0 = t >> 6;
    const int dbase = sg * 80 + (((sm >> 1) + (sg >> 1)) & 3) * 20 + (sm & 1);
#pragma unroll
    for (int k = 0; k < 2 * T; ++k) {
        const int vtap = k >> 1;
        const int chunk = k & 1;
        const int hh = (TH == 1) ? 1 : ((vtap / TW) * 2);
        const int ww = (TW == 1) ? 1 : ((vtap % TW) * 2);
        const int jflip = (2 - hh) * 3 + (2 - ww);  // compile-time flip
        const int l = chunk * 4 + l0;
        wlds[vtap * 640 + dbase + l * 2] = weight[(chunk * 256 + t) * 9 + jflip];
    }
}

// ---- stage the block's input tile [yi][xi<12][cpad] (zero-filled OOB) ----
template <int NROWS, int NCHUNK>
__device__ __forceinline__ void stage_input(const float* __restrict__ in,
                                            float* __restrict__ ilds,
                                            int t, int n, int y0, int x0) {
    const int c = t >> 2, r = t & 3;
    const int cpad = c + 4 * (c >> 3);  // R3: bank-spread channel offset
#pragma unroll
    for (int pp = r; pp < NROWS * NCHUNK; pp += 4) {
        const int yi = pp / NCHUNK, ch = pp % NCHUNK; // compile-time folds
        const int y = y0 + yi;
        const int xc = x0 + ch * 4;
        float4 vv = {0.f, 0.f, 0.f, 0.f};
        if (y < HIN && xc < WIN)
            vv = *(const float4*)(in + (((size_t)(n * 64 + c) * HIN + y) * WIN + xc));
        ilds[(yi * 12 + ch * 4 + 0) * IROW + cpad] = vv.x;
        ilds[(yi * 12 + ch * 4 + 1) * IROW + cpad] = vv.y;
        ilds[(yi * 12 + ch * 4 + 2) * IROW + cpad] = vv.z;
        ilds[(yi * 12 + ch * 4 + 3) * IROW + cpad] = vv.w;
    }
}

// ---- priors for one position q (m-dim packed f2; invalid taps -> zero votes)
template <int TH, int TW>
__device__ __forceinline__ void compute_pri(const float* __restrict__ ilds,
                                            const float* __restrict__ wlds,
                                            int q, int x0, int pi, int g, int s,
                                            f2 (&pri2)[TH * TW][4]) {
#pragma unroll
    for (int i = 0; i < TH; ++i) {
        const int y = (TH == 1) ? pi : (pi + i);
        const bool vy = (y < HIN);
#pragma unroll
        for (int j = 0; j < TW; ++j) {
            const int v = i * TW + j;
            const int w = (TW == 1) ? 1 : j * 2;
            const int x = (q + w - 1) >> 1;
            if (vy && x < WIN) {  // wave-uniform
                const float4* xp =
                    (const float4*)(ilds + (i * 12 + (x - x0)) * IROW + s * 12);
                float4 x0v = xp[0], x1v = xp[1];
                float xv[8] = {x0v.x, x0v.y, x0v.z, x0v.w, x1v.x, x1v.y, x1v.z, x1v.w};
                const float* wb = wlds + v * 640 + g * 80;
#pragma unroll
                for (int m2 = 0; m2 < 4; ++m2) {
                    const float4* row =
                        (const float4*)(wb + ((m2 + (g >> 1)) & 3) * 20);  // R3 rot
                    f2 acc = mk2(0.f, 0.f);
#pragma unroll
                    for (int k = 0; k < 4; ++k) {
                        float4 w4 = row[k];
                        acc = fma2(mk2(xv[2 * k], xv[2 * k]), mk2(w4.x, w4.y), acc);
                        acc = fma2(mk2(xv[2 * k + 1], xv[2 * k + 1]), mk2(w4.z, w4.w), acc);
                    }
                    pri2[v][m2] = acc;
                }
            } else {
#pragma unroll
                for (int m2 = 0; m2 < 4; ++m2) pri2[v][m2] = mk2(0.f, 0.f);
            }
        }
    }
}

// ---- R4-verified merged dual-position priors (passed, identical absmax):
// one wave computes q and q+8; every weight row loaded ONCE feeds both
// positions' fma chains. Per-wave b128 for T2: 72 -> 40, T1: 36 -> 20.
// Per-position arithmetic order unchanged (bit-identical results).
template <int TH, int TW>
__device__ __forceinline__ void compute_pri_dual(const float* __restrict__ ilds,
                                                 const float* __restrict__ wlds,
                                                 int qa, int x0, int pi, int g, int s,
                                                 f2 (&pa)[TH * TW][4],
                                                 f2 (&pb)[TH * TW][4]) {
#pragma unroll
    for (int i = 0; i < TH; ++i) {
        const int y = (TH == 1) ? pi : (pi + i);
        const bool vy = (y < HIN);
#pragma unroll
        for (int j = 0; j < TW; ++j) {
            const int v = i * TW + j;
            const int w = (TW == 1) ? 1 : j * 2;
            const int xa = (qa + w - 1) >> 1;
            const int xb = xa + 4;  // position q+8 -> x shifts by +4
            const bool oka = vy && (xa < WIN);  // wave-uniform
            const bool okb = vy && (xb < WIN);  // wave-uniform
            float xva[8], xvb[8];
            if (oka) {
                const float4* xp =
                    (const float4*)(ilds + (i * 12 + (xa - x0)) * IROW + s * 12);
                float4 u0 = xp[0], u1 = xp[1];
                xva[0] = u0.x; xva[1] = u0.y; xva[2] = u0.z; xva[3] = u0.w;
                xva[4] = u1.x; xva[5] = u1.y; xva[6] = u1.z; xva[7] = u1.w;
            }
            if (okb) {
                const float4* xp =
                    (const float4*)(ilds + (i * 12 + (xb - x0)) * IROW + s * 12);
                float4 u0 = xp[0], u1 = xp[1];
                xvb[0] = u0.x; xvb[1] = u0.y; xvb[2] = u0.z; xvb[3] = u0.w;
                xvb[4] = u1.x; xvb[5] = u1.y; xvb[6] = u1.z; xvb[7] = u1.w;
            }
            if (oka || okb) {
                const float* wb = wlds + v * 640 + g * 80;
#pragma unroll
                for (int m2 = 0; m2 < 4; ++m2) {
                    const float4* row =
                        (const float4*)(wb + ((m2 + (g >> 1)) & 3) * 20);
                    float4 rw[4] = {row[0], row[1], row[2], row[3]};
                    if (oka) {
                        f2 acc = mk2(0.f, 0.f);
#pragma unroll
                        for (int k = 0; k < 4; ++k) {
                            acc = fma2(mk2(xva[2 * k], xva[2 * k]),
                                       mk2(rw[k].x, rw[k].y), acc);
                            acc = fma2(mk2(xva[2 * k + 1], xva[2 * k + 1]),
                                       mk2(rw[k].z, rw[k].w), acc);
                        }
                        pa[v][m2] = acc;
                    } else {
                        pa[v][m2] = mk2(0.f, 0.f);
                    }
                    if (okb) {
                        f2 acc = mk2(0.f, 0.f);
#pragma unroll
                        for (int k = 0; k < 4; ++k) {
                            acc = fma2(mk2(xvb[2 * k], xvb[2 * k]),
                                       mk2(rw[k].x, rw[k].y), acc);
                            acc = fma2(mk2(xvb[2 * k + 1], xvb[2 * k + 1]),
                                       mk2(rw[k].z, rw[k].w), acc);
                        }
                        pb[v][m2] = acc;
                    } else {
                        pb[v][m2] = mk2(0.f, 0.f);
                    }
                }
            } else {
#pragma unroll
                for (int m2 = 0; m2 < 4; ++m2) {
                    pa[v][m2] = mk2(0.f, 0.f);
                    pb[v][m2] = mk2(0.f, 0.f);
                }
            }
        }
    }
}

// ---- full routing for one position: unnormalized r[] carried across iters
// (normalize is scale-invariant); zero votes add Z = 72-8T to the deferred
// softmax denominator. exp2-domain softmax (R0), exact rewrite.
template <int T>
__device__ __forceinline__ float route_core(const f2 (&pri2)[T][4],
                                            const float* __restrict__ bias,
                                            int g, int s) {
    constexpr float Z = (float)(72 - 8 * T);
    f2 rr[4];
#pragma unroll
    for (int m2 = 0; m2 < 4; ++m2) {
        f2 a = mk2(0.f, 0.f);
#pragma unroll
        for (int v = 0; v < T; ++v) a += pri2[v][m2];
        rr[m2].x = sum8(a.x);
        rr[m2].y = sum8(a.y);
    }
    float r8v = 0.f;
#pragma unroll
    for (int it = 0; it < NITER; ++it) {
        f2 t2 = mk2(0.f, 0.f);
#pragma unroll
        for (int m2 = 0; m2 < 4; ++m2) t2 = fma2(rr[m2], rr[m2], t2);
        const float sn = t2.x + t2.y;
        const float inv = __builtin_amdgcn_rsqf(fmaxf(sn, 1e-24f)) * 1.44269504f;
        const f2 inv2 = mk2(inv, inv);
        f2 on2[4];
#pragma unroll
        for (int m2 = 0; m2 < 4; ++m2) on2[m2] = rr[m2] * inv2;

        float a8 = 0.f;
        f2 acc2[4];
#pragma unroll
        for (int m2 = 0; m2 < 4; ++m2) acc2[m2] = mk2(0.f, 0.f);
#pragma unroll
        for (int v = 0; v < T; ++v) {
            f2 d2 = mk2(0.f, 0.f);
#pragma unroll
            for (int m2 = 0; m2 < 4; ++m2) d2 = fma2(pri2[v][m2], on2[m2], d2);
            const float e = __builtin_exp2f(d2.x + d2.y);
            a8 += e;
            const f2 e2 = mk2(e, e);
#pragma unroll
            for (int m2 = 0; m2 < 4; ++m2) acc2[m2] = fma2(e2, pri2[v][m2], acc2[m2]);
        }
#pragma unroll
        for (int m2 = 0; m2 < 4; ++m2) {
            rr[m2].x = sum8(acc2[m2].x);
            rr[m2].y = sum8(acc2[m2].y);
        }
        if (it == NITER - 1) r8v = sum8(a8);
    }
    const float invs = __builtin_amdgcn_rcpf(r8v + Z);  // zero votes: exp2(0)=1
    const f2 invs2 = mk2(invs, invs);
    f2 o2[4];
#pragma unroll
    for (int m2 = 0; m2 < 4; ++m2) o2[m2] = rr[m2] * invs2;
    f2 s2 = mk2(0.f, 0.f);
#pragma unroll
    for (int m2 = 0; m2 < 4; ++m2) s2 = fma2(o2[m2], o2[m2], s2);
    const float sn = s2.x + s2.y;
    const float factor =
        sn * __builtin_amdgcn_rcpf(1.f + sn) * __builtin_amdgcn_rsqf(sn + 1e-12f);
    f2 osel = o2[0];
#pragma unroll
    for (int m2 = 1; m2 < 4; ++m2)
        if ((s >> 1) == m2) osel = o2[m2];
    float val = (s & 1) ? osel.y : osel.x;
    return val * factor + bias[g * 8 + s];
}

// ---- dual-position path (T<=2): one wave does q and q+8. R8: now uses the
// R4-verified compute_pri_dual (weight reads shared across the 2 positions).
template <int TH, int TW>
__device__ __forceinline__ void run_dual(
    const float* __restrict__ in, const float* __restrict__ weight,
    const float* __restrict__ bias, float* __restrict__ out,
    float* __restrict__ ilds, float* __restrict__ wlds, float* __restrict__ olds,
    int t, int n, int p, int pi, int qb, int x0) {
    constexpr int T = TH * TW;
    stage_input<TH, (TW == 2 ? 3 : 2)>(in, ilds, t, n, pi, x0);
    stage_weights<TH, TW>(weight, wlds, t);
    __syncthreads();

    const int wave = t >> 6;
    const int lane = t & 63;
    const int g = lane >> 3;
    const int s = lane & 7;
    const int qa = qb + 2 * wave;

    f2 pa[T][4], pb[T][4];
    compute_pri_dual<TH, TW>(ilds, wlds, qa, x0, pi, g, s, pa, pb);

    const float va = route_core<T>(pa, bias, g, s);
    const float vb = route_core<T>(pb, bias, g, s);

    olds[lane * 9 + wave] = va;
    olds[lane * 9 + wave + 4] = vb;
    __syncthreads();
    const int c2 = t >> 2, w = t & 3;
    float* ob = out + (((size_t)n * 64 + c2) * 64 + p) * 64 + qb;
    ob[2 * w] = olds[c2 * 9 + w];
    ob[2 * w + 8] = olds[c2 * 9 + w + 4];
}

// ---- T=4 path: single position/wave (kept single: R4 proved dual-T4 makes
// it the critical pole, +30% kernel time) ----
__device__ __forceinline__ void run_t4(
    const float* __restrict__ in, const float* __restrict__ weight,
    const float* __restrict__ bias, float* __restrict__ out,
    float* __restrict__ ilds, float* __restrict__ wlds, float* __restrict__ olds,
    int t, int n, int p, int pi, int qb, int x0) {
    stage_input<2, 2>(in, ilds, t, n, pi, x0);
    stage_weights<2, 2>(weight, wlds, t);
    __syncthreads();

    const int wave = t >> 6;
    const int lane = t & 63;
    const int g = lane >> 3;
    const int s = lane & 7;

    f2 pa[4][4];
    compute_pri<2, 2>(ilds, wlds, qb + 2 * wave, x0, pi, g, s, pa);
    const float va = route_core<4>(pa, bias, g, s);

    olds[lane * 5 + wave] = va;
    __syncthreads();
    const int c2 = t >> 2, w = t & 3;
    out[(((size_t)n * 64 + c2) * 64 + p) * 64 + qb + 2 * w] = olds[c2 * 5 + w];
}

// Grid 1280, quadrant-interleaved: blockIdx%5 -> {T4,T4,T2v,T2h,T1}.
// Measurement model (R8 calibration): dur_us = 56.1us harness floor + k;
// k(R3) = 10.35us. This kernel targets the T2-dual pole (72 b128 + 2 routes).
__global__ __launch_bounds__(256, 5) void caps_routing(
    const float* __restrict__ in, const float* __restrict__ weight,
    const float* __restrict__ bias, float* __restrict__ out) {
    __shared__ float ilds[2 * 12 * IROW];  // input tile [yi][xi][cpad]
    __shared__ float wlds[4 * 640];        // staged taps (pk layout)
    __shared__ float olds[576];            // output staging
    const int t = threadIdx.x;

    const int b = blockIdx.x;
    const int grp = b / 5;        // 0..255
    const int sel = b - grp * 5;  // 0..4

    if (sel < 2) {  // T4: p odd, q odd; 512 blocks, 4 positions each
        const int idx = grp * 2 + sel;
        const int n = idx >> 8, r = idx & 255;
        const int pi = r >> 3, jq = r & 7;
        run_t4(in, weight, bias, out, ilds, wlds, olds,
               t, n, 2 * pi + 1, pi, 8 * jq + 1, 4 * jq);
    } else {  // dual paths: 256 blocks each, 8 positions each
        const int n = grp >> 7, r = grp & 127;
        const int pi = r >> 2, jq = r & 3;
        if (sel == 2)       // T2v: p odd, q even
            run_dual<2, 1>(in, weight, bias, out, ilds, wlds, olds,
                           t, n, 2 * pi + 1, pi, 16 * jq, 8 * jq);
        else if (sel == 3)  // T2h: p even, q odd
            run_dual<1, 2>(in, weight, bias, out, ilds, wlds, olds,
                           t, n, 2 * pi, pi, 16 * jq + 1, 8 * jq);
        else                // T1: p even, q even
            run_dual<1, 1>(in, weight, bias, out, ilds, wlds, olds,
                           t, n, 2 * pi, pi, 16 * jq, 8 * jq);
    }
}

extern "C" void kernel_launch(void* const* d_in, const int* in_sizes, int n_in,
                              void* d_out, int out_size, void* d_ws, size_t ws_size,
                              hipStream_t stream) {
    const float* in = (const float*)d_in[0];
    const float* weight = (const float*)d_in[1];
    const float* bias = (const float*)d_in[2];
    float* out = (float*)d_out;
    (void)d_ws; (void)ws_size;

    caps_routing<<<1280, 256, 0, stream>>>(in, weight, bias, out);
}